// Round 1
// baseline (804.992 us; speedup 1.0000x reference)
//
#include <hip/hip_runtime.h>
#include <cstdint>
#include <cstddef>

#define NEG_SLOPE 0.2f

// ---------------------------------------------------------------------------
// CSR build: count -> scan (3 kernels) -> fill
// ---------------------------------------------------------------------------
__global__ void count_edges(const int* __restrict__ ei, int* __restrict__ cnt,
                            int E, int total) {
    int e = blockIdx.x * blockDim.x + threadIdx.x;
    if (e >= total) return;
    int dst = (e < E) ? ei[E + e] : (e - E);   // self-loops appended
    atomicAdd(&cnt[dst], 1);
}

__global__ void scan1(const int* __restrict__ cnt, int* __restrict__ part, int n) {
    __shared__ int red[256];
    int base = blockIdx.x * 1024;
    int s = 0;
    for (int i = threadIdx.x; i < 1024; i += 256) {
        int idx = base + i;
        s += (idx < n) ? cnt[idx] : 0;
    }
    red[threadIdx.x] = s;
    __syncthreads();
    for (int off = 128; off; off >>= 1) {
        if (threadIdx.x < off) red[threadIdx.x] += red[threadIdx.x + off];
        __syncthreads();
    }
    if (threadIdx.x == 0) part[blockIdx.x] = red[0];
}

// single block: exclusive scan of partials (nb <= 256); also writes rp[n]=total
__global__ void scan2(int* __restrict__ part, int nb, int* __restrict__ rp, int n) {
    __shared__ int sc[256];
    int t = threadIdx.x;
    int v = (t < nb) ? part[t] : 0;
    sc[t] = v;
    __syncthreads();
    for (int off = 1; off < 256; off <<= 1) {
        int x = (t >= off) ? sc[t - off] : 0;
        __syncthreads();
        sc[t] += x;
        __syncthreads();
    }
    if (t < nb) part[t] = sc[t] - v;        // exclusive
    if (t == 255) rp[n] = sc[255];          // total edge count
}

__global__ void scan3(const int* __restrict__ cnt, const int* __restrict__ part,
                      int* __restrict__ rp, int* __restrict__ cursor, int n) {
    __shared__ int tsum[256];
    int base = blockIdx.x * 1024;
    int t = threadIdx.x;
    int v[4];
    int loc = 0;
#pragma unroll
    for (int i = 0; i < 4; ++i) {
        int idx = base + t * 4 + i;
        v[i] = (idx < n) ? cnt[idx] : 0;
        loc += v[i];
    }
    tsum[t] = loc;
    __syncthreads();
    for (int off = 1; off < 256; off <<= 1) {
        int x = (t >= off) ? tsum[t - off] : 0;
        __syncthreads();
        tsum[t] += x;
        __syncthreads();
    }
    int excl = tsum[t] - loc + part[blockIdx.x];
#pragma unroll
    for (int i = 0; i < 4; ++i) {
        int idx = base + t * 4 + i;
        if (idx < n) { rp[idx] = excl; cursor[idx] = excl; }
        excl += v[i];
    }
}

__global__ void fill_edges(const int* __restrict__ ei, int* __restrict__ cursor,
                           int* __restrict__ cs, int E, int total) {
    int e = blockIdx.x * blockDim.x + threadIdx.x;
    if (e >= total) return;
    int src, dst;
    if (e < E) { src = ei[e]; dst = ei[E + e]; }
    else       { src = dst = e - E; }
    int pos = atomicAdd(&cursor[dst], 1);
    cs[pos] = src;
}

// ---------------------------------------------------------------------------
// Fused projection + attention dots:  h = x @ W ; hs = h@a_s ; hd = h@a_d
// Register blocking: each thread computes 4 nodes x 4 features.
// W staged in LDS (b128 reads); x read as broadcast global float4.
// ---------------------------------------------------------------------------
template <int INF, int OUTF>
__global__ void gemm_attn(const float* __restrict__ x, const float* __restrict__ W,
                          const float* __restrict__ a_s, const float* __restrict__ a_d,
                          float* __restrict__ h, float* __restrict__ hs,
                          float* __restrict__ hd, int n) {
    constexpr int FC  = OUTF / 4;          // threads along feature dim
    constexpr int NPB = 64;                // nodes per block
    constexpr int NT  = FC * (NPB / 4);    // threads per block
    __shared__ float Wl[INF * OUTF];
    int tid = threadIdx.x;
    for (int i = tid; i < INF * OUTF; i += NT) Wl[i] = W[i];
    __syncthreads();

    int fc = tid % FC;
    int nc = tid / FC;                     // 0..15
    int n0 = blockIdx.x * NPB + nc * 4;
    int ni[4];
#pragma unroll
    for (int i = 0; i < 4; ++i) { int v = n0 + i; ni[i] = (v < n) ? v : (n - 1); }

    float acc[4][4] = {};
#pragma unroll 2
    for (int k = 0; k < INF; k += 4) {
        float4 xv[4];
#pragma unroll
        for (int i = 0; i < 4; ++i)
            xv[i] = *reinterpret_cast<const float4*>(&x[(size_t)ni[i] * INF + k]);
#pragma unroll
        for (int j = 0; j < 4; ++j) {
            float4 wv = *reinterpret_cast<const float4*>(&Wl[(k + j) * OUTF + fc * 4]);
#pragma unroll
            for (int i = 0; i < 4; ++i) {
                float xs = (&xv[i].x)[j];
                acc[i][0] = fmaf(xs, wv.x, acc[i][0]);
                acc[i][1] = fmaf(xs, wv.y, acc[i][1]);
                acc[i][2] = fmaf(xs, wv.z, acc[i][2]);
                acc[i][3] = fmaf(xs, wv.w, acc[i][3]);
            }
        }
    }

    float asv[4], adv[4];
#pragma unroll
    for (int j = 0; j < 4; ++j) { asv[j] = a_s[fc * 4 + j]; adv[j] = a_d[fc * 4 + j]; }

#pragma unroll
    for (int i = 0; i < 4; ++i) {
        float ps = acc[i][0] * asv[0] + acc[i][1] * asv[1] +
                   acc[i][2] * asv[2] + acc[i][3] * asv[3];
        float pd = acc[i][0] * adv[0] + acc[i][1] * adv[1] +
                   acc[i][2] * adv[2] + acc[i][3] * adv[3];
#pragma unroll
        for (int off = FC >> 1; off; off >>= 1) {
            ps += __shfl_xor(ps, off, FC);
            pd += __shfl_xor(pd, off, FC);
        }
        int node = n0 + i;
        if (node < n) {
            *reinterpret_cast<float4*>(&h[(size_t)node * OUTF + fc * 4]) =
                make_float4(acc[i][0], acc[i][1], acc[i][2], acc[i][3]);
            if (fc == 0) { hs[node] = ps; hd[node] = pd; }
        }
    }
}

// ---------------------------------------------------------------------------
// Per-destination-node online-softmax aggregation. One wave per node,
// lane = feature. out[n][f] = relu( sum_e alpha_e * h[src_e][f] + b[f] )
// ---------------------------------------------------------------------------
template <int F>
__global__ __launch_bounds__(256) void aggregate(
    const float* __restrict__ h, const float* __restrict__ hs,
    const float* __restrict__ hd, const int* __restrict__ rp,
    const int* __restrict__ cs, const float* __restrict__ b,
    float* __restrict__ out, int n) {
    int wid  = (blockIdx.x * blockDim.x + threadIdx.x) >> 6;
    int lane = threadIdx.x & 63;
    if (wid >= n) return;
    int node = wid;
    int beg = rp[node], end = rp[node + 1];
    float hdn = hd[node];
    int fl = lane & (F - 1);
    float bb = b[fl];

    float m = -1e30f, s = 0.f, acc = 0.f;
    for (int j = beg; j < end; ++j) {
        int src = cs[j];
        float l = hs[src] + hdn;
        l = (l > 0.f) ? l : NEG_SLOPE * l;
        float mn = fmaxf(m, l);
        float sc = __expf(m - mn);
        float w  = __expf(l - mn);
        float hv = h[(size_t)src * F + fl];
        s   = fmaf(s, sc, w);
        acc = fmaf(acc, sc, w * hv);
        m = mn;
    }
    float res = acc / (s + 1e-16f) + bb;
    res = fmaxf(res, 0.f);
    if (lane < F) out[(size_t)node * F + lane] = res;
}

// ---------------------------------------------------------------------------
// Global mean pool (batch is sorted): LDS pre-reduction then global atomics
// ---------------------------------------------------------------------------
__global__ void pool_kernel(const float* __restrict__ x, const int* __restrict__ batch,
                            float* __restrict__ pool, float* __restrict__ gcnt, int n) {
    __shared__ float lp[64 * 32];
    __shared__ float lc[64];
    int tid = threadIdx.x;
    for (int i = tid; i < 64 * 32; i += 256) lp[i] = 0.f;
    if (tid < 64) lc[tid] = 0.f;
    __syncthreads();
    int f = tid % 32, r = tid / 32;
    int base = blockIdx.x * 64;
    for (int i = r; i < 64; i += 8) {
        int node = base + i;
        if (node < n) {
            int g = batch[node];
            atomicAdd(&lp[g * 32 + f], x[(size_t)node * 32 + f]);
            if (f == 0) atomicAdd(&lc[g], 1.f);
        }
    }
    __syncthreads();
    for (int i = tid; i < 64 * 32; i += 256)
        if (lp[i] != 0.f) atomicAdd(&pool[i], lp[i]);
    if (tid < 64 && lc[tid] != 0.f) atomicAdd(&gcnt[tid], lc[tid]);
}

__global__ void finalize(const float* __restrict__ pool, const float* __restrict__ gcnt,
                         float* __restrict__ out, int total) {
    int i = blockIdx.x * blockDim.x + threadIdx.x;
    if (i >= total) return;
    out[i] = pool[i] / fmaxf(gcnt[i / 32], 1.f);
}

// ---------------------------------------------------------------------------
extern "C" void kernel_launch(void* const* d_in, const int* in_sizes, int n_in,
                              void* d_out, int out_size, void* d_ws, size_t ws_size,
                              hipStream_t stream) {
    const float* x    = (const float*)d_in[0];
    const int*   ei   = (const int*)d_in[1];
    const int*   batch= (const int*)d_in[2];
    const float* W1   = (const float*)d_in[3];
    const float* as1  = (const float*)d_in[4];
    const float* ad1  = (const float*)d_in[5];
    const float* b1   = (const float*)d_in[6];
    const float* W2   = (const float*)d_in[7];
    const float* as2  = (const float*)d_in[8];
    const float* ad2  = (const float*)d_in[9];
    const float* b2   = (const float*)d_in[10];
    const float* W3   = (const float*)d_in[11];
    const float* as3  = (const float*)d_in[12];
    const float* ad3  = (const float*)d_in[13];
    const float* b3   = (const float*)d_in[14];
    float* out = (float*)d_out;

    const int N  = in_sizes[0] / 128;
    const int E  = in_sizes[1] / 2;
    const int ET = E + N;
    const int G  = 64;

    char* p = (char*)d_ws;
    auto alloc = [&](size_t bytes) {
        char* r = p;
        p += (bytes + 255) & ~(size_t)255;
        return r;
    };
    int*   cnt    = (int*)alloc((size_t)N * 4);
    int*   rp     = (int*)alloc((size_t)(N + 1) * 4);
    int*   cursor = (int*)alloc((size_t)N * 4);
    int*   part   = (int*)alloc(1024);
    int*   cs     = (int*)alloc((size_t)ET * 4);
    float* hbuf   = (float*)alloc((size_t)N * 64 * 4);
    float* hs     = (float*)alloc((size_t)N * 4);
    float* hd     = (float*)alloc((size_t)N * 4);
    float* xA     = (float*)alloc((size_t)N * 64 * 4);
    float* xB     = (float*)alloc((size_t)N * 64 * 4);
    float* pool   = (float*)alloc((size_t)G * 32 * 4);
    float* gcnt   = (float*)alloc((size_t)G * 4);

    // ---- CSR by destination (shared across all 3 layers) ----
    hipMemsetAsync(cnt, 0, (size_t)N * 4, stream);
    int eb = (ET + 255) / 256;
    count_edges<<<eb, 256, 0, stream>>>(ei, cnt, E, ET);
    int nb = (N + 1023) / 1024;
    scan1<<<nb, 256, 0, stream>>>(cnt, part, N);
    scan2<<<1, 256, 0, stream>>>(part, nb, rp, N);
    scan3<<<nb, 256, 0, stream>>>(cnt, part, rp, cursor, N);
    fill_edges<<<eb, 256, 0, stream>>>(ei, cursor, cs, E, ET);

    int gb = (N + 63) / 64;
    int ab = (N + 3) / 4;

    // ---- layer 1: 128 -> 64 ----
    gemm_attn<128, 64><<<gb, 256, 0, stream>>>(x, W1, as1, ad1, hbuf, hs, hd, N);
    aggregate<64><<<ab, 256, 0, stream>>>(hbuf, hs, hd, rp, cs, b1, xA, N);
    // ---- layer 2: 64 -> 64 ----
    gemm_attn<64, 64><<<gb, 256, 0, stream>>>(xA, W2, as2, ad2, hbuf, hs, hd, N);
    aggregate<64><<<ab, 256, 0, stream>>>(hbuf, hs, hd, rp, cs, b2, xB, N);
    // ---- layer 3: 64 -> 32 ----
    gemm_attn<64, 32><<<gb, 128, 0, stream>>>(xB, W3, as3, ad3, hbuf, hs, hd, N);
    aggregate<32><<<ab, 256, 0, stream>>>(hbuf, hs, hd, rp, cs, b3, xA, N);

    // ---- global mean pool ----
    hipMemsetAsync(pool, 0, (size_t)G * 32 * 4, stream);
    hipMemsetAsync(gcnt, 0, (size_t)G * 4, stream);
    pool_kernel<<<(N + 63) / 64, 256, 0, stream>>>(xA, batch, pool, gcnt, N);
    finalize<<<(G * 32 + 255) / 256, 256, 0, stream>>>(pool, gcnt, out, G * 32);
}

// Round 2
// 525.980 us; speedup vs baseline: 1.5305x; 1.5305x over previous
//
#include <hip/hip_runtime.h>
#include <cstdint>
#include <cstddef>

#define NEG_SLOPE 0.2f

// ---------------------------------------------------------------------------
// CSR build: count -> scan (3 kernels) -> fill
// ---------------------------------------------------------------------------
__global__ void count_edges(const int* __restrict__ ei, int* __restrict__ cnt,
                            int E, int total) {
    int e = blockIdx.x * blockDim.x + threadIdx.x;
    if (e >= total) return;
    int dst = (e < E) ? ei[E + e] : (e - E);   // self-loops appended
    atomicAdd(&cnt[dst], 1);
}

__global__ void scan1(const int* __restrict__ cnt, int* __restrict__ part, int n) {
    __shared__ int red[256];
    int base = blockIdx.x * 1024;
    int s = 0;
    for (int i = threadIdx.x; i < 1024; i += 256) {
        int idx = base + i;
        s += (idx < n) ? cnt[idx] : 0;
    }
    red[threadIdx.x] = s;
    __syncthreads();
    for (int off = 128; off; off >>= 1) {
        if (threadIdx.x < off) red[threadIdx.x] += red[threadIdx.x + off];
        __syncthreads();
    }
    if (threadIdx.x == 0) part[blockIdx.x] = red[0];
}

// single block: exclusive scan of partials (nb <= 256); also writes rp[n]=total
__global__ void scan2(int* __restrict__ part, int nb, int* __restrict__ rp, int n) {
    __shared__ int sc[256];
    int t = threadIdx.x;
    int v = (t < nb) ? part[t] : 0;
    sc[t] = v;
    __syncthreads();
    for (int off = 1; off < 256; off <<= 1) {
        int x = (t >= off) ? sc[t - off] : 0;
        __syncthreads();
        sc[t] += x;
        __syncthreads();
    }
    if (t < nb) part[t] = sc[t] - v;        // exclusive
    if (t == 255) rp[n] = sc[255];          // total edge count
}

__global__ void scan3(const int* __restrict__ cnt, const int* __restrict__ part,
                      int* __restrict__ rp, int* __restrict__ cursor, int n) {
    __shared__ int tsum[256];
    int base = blockIdx.x * 1024;
    int t = threadIdx.x;
    int v[4];
    int loc = 0;
#pragma unroll
    for (int i = 0; i < 4; ++i) {
        int idx = base + t * 4 + i;
        v[i] = (idx < n) ? cnt[idx] : 0;
        loc += v[i];
    }
    tsum[t] = loc;
    __syncthreads();
    for (int off = 1; off < 256; off <<= 1) {
        int x = (t >= off) ? tsum[t - off] : 0;
        __syncthreads();
        tsum[t] += x;
        __syncthreads();
    }
    int excl = tsum[t] - loc + part[blockIdx.x];
#pragma unroll
    for (int i = 0; i < 4; ++i) {
        int idx = base + t * 4 + i;
        if (idx < n) { rp[idx] = excl; cursor[idx] = excl; }
        excl += v[i];
    }
}

__global__ void fill_edges(const int* __restrict__ ei, int* __restrict__ cursor,
                           int* __restrict__ cs, int E, int total) {
    int e = blockIdx.x * blockDim.x + threadIdx.x;
    if (e >= total) return;
    int src, dst;
    if (e < E) { src = ei[e]; dst = ei[E + e]; }
    else       { src = dst = e - E; }
    int pos = atomicAdd(&cursor[dst], 1);
    cs[pos] = src;
}

// ---------------------------------------------------------------------------
// Fused projection + attention dots:  h = x @ W ; hs = h@a_s ; hd = h@a_d
// ---------------------------------------------------------------------------
template <int INF, int OUTF>
__global__ void gemm_attn(const float* __restrict__ x, const float* __restrict__ W,
                          const float* __restrict__ a_s, const float* __restrict__ a_d,
                          float* __restrict__ h, float* __restrict__ hs,
                          float* __restrict__ hd, int n) {
    constexpr int FC  = OUTF / 4;          // threads along feature dim
    constexpr int NPB = 64;                // nodes per block
    constexpr int NT  = FC * (NPB / 4);    // threads per block
    __shared__ float Wl[INF * OUTF];
    int tid = threadIdx.x;
    for (int i = tid; i < INF * OUTF; i += NT) Wl[i] = W[i];
    __syncthreads();

    int fc = tid % FC;
    int nc = tid / FC;                     // 0..15
    int n0 = blockIdx.x * NPB + nc * 4;
    int ni[4];
#pragma unroll
    for (int i = 0; i < 4; ++i) { int v = n0 + i; ni[i] = (v < n) ? v : (n - 1); }

    float acc[4][4] = {};
#pragma unroll 2
    for (int k = 0; k < INF; k += 4) {
        float4 xv[4];
#pragma unroll
        for (int i = 0; i < 4; ++i)
            xv[i] = *reinterpret_cast<const float4*>(&x[(size_t)ni[i] * INF + k]);
#pragma unroll
        for (int j = 0; j < 4; ++j) {
            float4 wv = *reinterpret_cast<const float4*>(&Wl[(k + j) * OUTF + fc * 4]);
#pragma unroll
            for (int i = 0; i < 4; ++i) {
                float xs = (&xv[i].x)[j];
                acc[i][0] = fmaf(xs, wv.x, acc[i][0]);
                acc[i][1] = fmaf(xs, wv.y, acc[i][1]);
                acc[i][2] = fmaf(xs, wv.z, acc[i][2]);
                acc[i][3] = fmaf(xs, wv.w, acc[i][3]);
            }
        }
    }

    float asv[4], adv[4];
#pragma unroll
    for (int j = 0; j < 4; ++j) { asv[j] = a_s[fc * 4 + j]; adv[j] = a_d[fc * 4 + j]; }

#pragma unroll
    for (int i = 0; i < 4; ++i) {
        float ps = acc[i][0] * asv[0] + acc[i][1] * asv[1] +
                   acc[i][2] * asv[2] + acc[i][3] * asv[3];
        float pd = acc[i][0] * adv[0] + acc[i][1] * adv[1] +
                   acc[i][2] * adv[2] + acc[i][3] * adv[3];
#pragma unroll
        for (int off = FC >> 1; off; off >>= 1) {
            ps += __shfl_xor(ps, off, FC);
            pd += __shfl_xor(pd, off, FC);
        }
        int node = n0 + i;
        if (node < n) {
            *reinterpret_cast<float4*>(&h[(size_t)node * OUTF + fc * 4]) =
                make_float4(acc[i][0], acc[i][1], acc[i][2], acc[i][3]);
            if (fc == 0) { hs[node] = ps; hd[node] = pd; }
        }
    }
}

// ---------------------------------------------------------------------------
// Per-destination-node online-softmax aggregation. One wave per node,
// lane = feature. Edge loop chunked by U=8: all gathers within a chunk are
// independent (in flight simultaneously), (m,s,acc) rescaled once per chunk.
// Predicated tail (invalid slots -> logit -1e30 -> weight 0).
// ---------------------------------------------------------------------------
template <int F>
__global__ __launch_bounds__(256) void aggregate(
    const float* __restrict__ h, const float* __restrict__ hs,
    const float* __restrict__ hd, const int* __restrict__ rp,
    const int* __restrict__ cs, const float* __restrict__ b,
    float* __restrict__ out, int n) {
    int wid  = (blockIdx.x * blockDim.x + threadIdx.x) >> 6;
    int lane = threadIdx.x & 63;
    if (wid >= n) return;
    int node = wid;
    int beg = rp[node], end = rp[node + 1];
    float hdn = hd[node];
    int fl = lane & (F - 1);
    float bb = b[fl];

    constexpr int U = 8;
    float m = -1e30f, s = 0.f, acc = 0.f;

    for (int j = beg; j < end; j += U) {
        int srcs[U];
#pragma unroll
        for (int u = 0; u < U; ++u) {
            int idx = j + u;
            srcs[u] = cs[(idx < end) ? idx : (end - 1)];
        }
        float ls[U];
#pragma unroll
        for (int u = 0; u < U; ++u) ls[u] = hs[srcs[u]];
        float hv[U];
#pragma unroll
        for (int u = 0; u < U; ++u) hv[u] = h[(size_t)srcs[u] * F + fl];

        float lmax = -1e30f;
#pragma unroll
        for (int u = 0; u < U; ++u) {
            float l = ls[u] + hdn;
            l = (l > 0.f) ? l : NEG_SLOPE * l;
            ls[u] = (j + u < end) ? l : -1e30f;
            lmax = fmaxf(lmax, ls[u]);
        }
        float mn = fmaxf(m, lmax);
        float sc = __expf(m - mn);
        s *= sc;
        acc *= sc;
#pragma unroll
        for (int u = 0; u < U; ++u) {
            float w = __expf(ls[u] - mn);
            s += w;
            acc = fmaf(w, hv[u], acc);
        }
        m = mn;
    }

    float res = acc / (s + 1e-16f) + bb;
    res = fmaxf(res, 0.f);
    if (lane < F) out[(size_t)node * F + lane] = res;
}

// ---------------------------------------------------------------------------
// Global mean pool (batch is sorted): LDS pre-reduction then global atomics
// ---------------------------------------------------------------------------
__global__ void pool_kernel(const float* __restrict__ x, const int* __restrict__ batch,
                            float* __restrict__ pool, float* __restrict__ gcnt, int n) {
    __shared__ float lp[64 * 32];
    __shared__ float lc[64];
    int tid = threadIdx.x;
    for (int i = tid; i < 64 * 32; i += 256) lp[i] = 0.f;
    if (tid < 64) lc[tid] = 0.f;
    __syncthreads();
    int f = tid % 32, r = tid / 32;
    int base = blockIdx.x * 64;
    for (int i = r; i < 64; i += 8) {
        int node = base + i;
        if (node < n) {
            int g = batch[node];
            atomicAdd(&lp[g * 32 + f], x[(size_t)node * 32 + f]);
            if (f == 0) atomicAdd(&lc[g], 1.f);
        }
    }
    __syncthreads();
    for (int i = tid; i < 64 * 32; i += 256)
        if (lp[i] != 0.f) atomicAdd(&pool[i], lp[i]);
    if (tid < 64 && lc[tid] != 0.f) atomicAdd(&gcnt[tid], lc[tid]);
}

__global__ void finalize(const float* __restrict__ pool, const float* __restrict__ gcnt,
                         float* __restrict__ out, int total) {
    int i = blockIdx.x * blockDim.x + threadIdx.x;
    if (i >= total) return;
    out[i] = pool[i] / fmaxf(gcnt[i / 32], 1.f);
}

// ---------------------------------------------------------------------------
extern "C" void kernel_launch(void* const* d_in, const int* in_sizes, int n_in,
                              void* d_out, int out_size, void* d_ws, size_t ws_size,
                              hipStream_t stream) {
    const float* x    = (const float*)d_in[0];
    const int*   ei   = (const int*)d_in[1];
    const int*   batch= (const int*)d_in[2];
    const float* W1   = (const float*)d_in[3];
    const float* as1  = (const float*)d_in[4];
    const float* ad1  = (const float*)d_in[5];
    const float* b1   = (const float*)d_in[6];
    const float* W2   = (const float*)d_in[7];
    const float* as2  = (const float*)d_in[8];
    const float* ad2  = (const float*)d_in[9];
    const float* b2   = (const float*)d_in[10];
    const float* W3   = (const float*)d_in[11];
    const float* as3  = (const float*)d_in[12];
    const float* ad3  = (const float*)d_in[13];
    const float* b3   = (const float*)d_in[14];
    float* out = (float*)d_out;

    const int N  = in_sizes[0] / 128;
    const int E  = in_sizes[1] / 2;
    const int ET = E + N;
    const int G  = 64;

    char* p = (char*)d_ws;
    auto alloc = [&](size_t bytes) {
        char* r = p;
        p += (bytes + 255) & ~(size_t)255;
        return r;
    };
    int*   cnt    = (int*)alloc((size_t)N * 4);
    int*   rp     = (int*)alloc((size_t)(N + 1) * 4);
    int*   cursor = (int*)alloc((size_t)N * 4);
    int*   part   = (int*)alloc(1024);
    int*   cs     = (int*)alloc((size_t)ET * 4);
    float* hbuf   = (float*)alloc((size_t)N * 64 * 4);
    float* hs     = (float*)alloc((size_t)N * 4);
    float* hd     = (float*)alloc((size_t)N * 4);
    float* xA     = (float*)alloc((size_t)N * 64 * 4);
    float* xB     = (float*)alloc((size_t)N * 64 * 4);
    float* pool   = (float*)alloc((size_t)G * 32 * 4);
    float* gcnt   = (float*)alloc((size_t)G * 4);

    // ---- CSR by destination (shared across all 3 layers) ----
    hipMemsetAsync(cnt, 0, (size_t)N * 4, stream);
    int eb = (ET + 255) / 256;
    count_edges<<<eb, 256, 0, stream>>>(ei, cnt, E, ET);
    int nb = (N + 1023) / 1024;
    scan1<<<nb, 256, 0, stream>>>(cnt, part, N);
    scan2<<<1, 256, 0, stream>>>(part, nb, rp, N);
    scan3<<<nb, 256, 0, stream>>>(cnt, part, rp, cursor, N);
    fill_edges<<<eb, 256, 0, stream>>>(ei, cursor, cs, E, ET);

    int gb = (N + 63) / 64;
    int ab = (N + 3) / 4;

    // ---- layer 1: 128 -> 64 ----
    gemm_attn<128, 64><<<gb, 256, 0, stream>>>(x, W1, as1, ad1, hbuf, hs, hd, N);
    aggregate<64><<<ab, 256, 0, stream>>>(hbuf, hs, hd, rp, cs, b1, xA, N);
    // ---- layer 2: 64 -> 64 ----
    gemm_attn<64, 64><<<gb, 256, 0, stream>>>(xA, W2, as2, ad2, hbuf, hs, hd, N);
    aggregate<64><<<ab, 256, 0, stream>>>(hbuf, hs, hd, rp, cs, b2, xB, N);
    // ---- layer 3: 64 -> 32 ----
    gemm_attn<64, 32><<<gb, 128, 0, stream>>>(xB, W3, as3, ad3, hbuf, hs, hd, N);
    aggregate<32><<<ab, 256, 0, stream>>>(hbuf, hs, hd, rp, cs, b3, xA, N);

    // ---- global mean pool ----
    hipMemsetAsync(pool, 0, (size_t)G * 32 * 4, stream);
    hipMemsetAsync(gcnt, 0, (size_t)G * 4, stream);
    pool_kernel<<<(N + 63) / 64, 256, 0, stream>>>(xA, batch, pool, gcnt, N);
    finalize<<<(G * 32 + 255) / 256, 256, 0, stream>>>(pool, gcnt, out, G * 32);
}

// Round 3
// 434.460 us; speedup vs baseline: 1.8529x; 1.2107x over previous
//
#include <hip/hip_runtime.h>
#include <cstdint>
#include <cstddef>

#define NEG_SLOPE 0.2f

// ---------------------------------------------------------------------------
// CSR build: count -> scan (3 kernels) -> bin -> local fill
// ---------------------------------------------------------------------------
__global__ void count_edges(const int* __restrict__ ei, int* __restrict__ cnt,
                            int E, int total) {
    int e = blockIdx.x * blockDim.x + threadIdx.x;
    if (e >= total) return;
    int dst = (e < E) ? ei[E + e] : (e - E);   // self-loops appended
    atomicAdd(&cnt[dst], 1);
}

__global__ void scan1(const int* __restrict__ cnt, int* __restrict__ part, int n) {
    __shared__ int red[256];
    int base = blockIdx.x * 1024;
    int s = 0;
    for (int i = threadIdx.x; i < 1024; i += 256) {
        int idx = base + i;
        s += (idx < n) ? cnt[idx] : 0;
    }
    red[threadIdx.x] = s;
    __syncthreads();
    for (int off = 128; off; off >>= 1) {
        if (threadIdx.x < off) red[threadIdx.x] += red[threadIdx.x + off];
        __syncthreads();
    }
    if (threadIdx.x == 0) part[blockIdx.x] = red[0];
}

// single block: exclusive scan of partials (nb <= 256); also writes rp[n]=total
__global__ void scan2(int* __restrict__ part, int nb, int* __restrict__ rp, int n) {
    __shared__ int sc[256];
    int t = threadIdx.x;
    int v = (t < nb) ? part[t] : 0;
    sc[t] = v;
    __syncthreads();
    for (int off = 1; off < 256; off <<= 1) {
        int x = (t >= off) ? sc[t - off] : 0;
        __syncthreads();
        sc[t] += x;
        __syncthreads();
    }
    if (t < nb) part[t] = sc[t] - v;        // exclusive
    if (t == 255) rp[n] = sc[255];          // total edge count
}

__global__ void scan3(const int* __restrict__ cnt, const int* __restrict__ part,
                      int* __restrict__ rp, int n) {
    __shared__ int tsum[256];
    int base = blockIdx.x * 1024;
    int t = threadIdx.x;
    int v[4];
    int loc = 0;
#pragma unroll
    for (int i = 0; i < 4; ++i) {
        int idx = base + t * 4 + i;
        v[i] = (idx < n) ? cnt[idx] : 0;
        loc += v[i];
    }
    tsum[t] = loc;
    __syncthreads();
    for (int off = 1; off < 256; off <<= 1) {
        int x = (t >= off) ? tsum[t - off] : 0;
        __syncthreads();
        tsum[t] += x;
        __syncthreads();
    }
    int excl = tsum[t] - loc + part[blockIdx.x];
#pragma unroll
    for (int i = 0; i < 4; ++i) {
        int idx = base + t * 4 + i;
        if (idx < n) rp[idx] = excl;
        excl += v[i];
    }
}

// bucket cursors = CSR offset of each bucket's first node (bucket = 512 nodes)
__global__ void bcur_init(const int* __restrict__ rp, int* __restrict__ bcur,
                          int n, int nb) {
    int t = threadIdx.x;
    if (t < nb) bcur[t] = rp[min(t * 512, n)];
    else if (t < 256) bcur[t] = 0;
}

// ---------------------------------------------------------------------------
// Pass 1: bin edges into 512-node coarse buckets. Per block: LDS histogram,
// one global atomic per touched bucket to reserve a contiguous run, then
// write (src,dst) pairs in per-bucket contiguous runs (~170B each) -> ebuf.
// ---------------------------------------------------------------------------
#define BIN_K 16   // edges per thread; chunk = 256*16 = 4096
__global__ __launch_bounds__(256) void bin_edges(
    const int* __restrict__ ei, int* __restrict__ bcur,
    int2* __restrict__ ebuf, int E, int total) {
    __shared__ int lhist[256];
    __shared__ int lbase[256];
    int tid = threadIdx.x;
    lhist[tid] = 0;
    __syncthreads();
    int base_e = blockIdx.x * (256 * BIN_K);
    int s[BIN_K], d[BIN_K], bk[BIN_K];
#pragma unroll
    for (int k = 0; k < BIN_K; ++k) {
        int e = base_e + tid + k * 256;
        bool v = e < total;
        int ee = v ? e : 0;
        if (ee < E) { s[k] = ei[ee]; d[k] = ei[E + ee]; }
        else        { s[k] = d[k] = ee - E; }
        bk[k] = v ? (d[k] >> 9) : -1;
        if (v) atomicAdd(&lhist[bk[k]], 1);
    }
    __syncthreads();
    int h = lhist[tid];
    lbase[tid] = (h > 0) ? atomicAdd(&bcur[tid], h) : 0;
    __syncthreads();
    lhist[tid] = 0;
    __syncthreads();
#pragma unroll
    for (int k = 0; k < BIN_K; ++k) {
        if (bk[k] >= 0) {
            int r = atomicAdd(&lhist[bk[k]], 1);
            ebuf[(size_t)lbase[bk[k]] + r] = make_int2(s[k], d[k]);
        }
    }
}

// ---------------------------------------------------------------------------
// Pass 2: one block per bucket. Node cursors live in LDS (no global atomics);
// cs writes confined to this bucket's ~35KB window -> one XCD fills each line.
// ---------------------------------------------------------------------------
__global__ __launch_bounds__(256) void local_fill(
    const int2* __restrict__ ebuf, const int* __restrict__ rp,
    int* __restrict__ cs, int n) {
    __shared__ int lcur[512];
    int node0 = blockIdx.x * 512;
    int nodes = min(512, n - node0);
    int tid = threadIdx.x;
    for (int j = tid; j < nodes; j += 256) lcur[j] = rp[node0 + j];
    __syncthreads();
    int beg = rp[node0];
    int end = rp[node0 + nodes];
    for (int base = beg; base < end; base += 256 * 8) {
        int2 pr[8];
        int idx[8];
#pragma unroll
        for (int u = 0; u < 8; ++u) {
            idx[u] = base + tid + u * 256;
            pr[u] = ebuf[(idx[u] < end) ? idx[u] : beg];
        }
#pragma unroll
        for (int u = 0; u < 8; ++u) {
            if (idx[u] < end) {
                int pos = atomicAdd(&lcur[pr[u].y - node0], 1);
                cs[pos] = pr[u].x;
            }
        }
    }
}

// ---------------------------------------------------------------------------
// Fused projection + attention dots:  h = x @ W ; hs = h@a_s ; hd = h@a_d
// ---------------------------------------------------------------------------
template <int INF, int OUTF>
__global__ void gemm_attn(const float* __restrict__ x, const float* __restrict__ W,
                          const float* __restrict__ a_s, const float* __restrict__ a_d,
                          float* __restrict__ h, float* __restrict__ hs,
                          float* __restrict__ hd, int n) {
    constexpr int FC  = OUTF / 4;          // threads along feature dim
    constexpr int NPB = 64;                // nodes per block
    constexpr int NT  = FC * (NPB / 4);    // threads per block
    __shared__ float Wl[INF * OUTF];
    int tid = threadIdx.x;
    for (int i = tid; i < INF * OUTF; i += NT) Wl[i] = W[i];
    __syncthreads();

    int fc = tid % FC;
    int nc = tid / FC;                     // 0..15
    int n0 = blockIdx.x * NPB + nc * 4;
    int ni[4];
#pragma unroll
    for (int i = 0; i < 4; ++i) { int v = n0 + i; ni[i] = (v < n) ? v : (n - 1); }

    float acc[4][4] = {};
#pragma unroll 2
    for (int k = 0; k < INF; k += 4) {
        float4 xv[4];
#pragma unroll
        for (int i = 0; i < 4; ++i)
            xv[i] = *reinterpret_cast<const float4*>(&x[(size_t)ni[i] * INF + k]);
#pragma unroll
        for (int j = 0; j < 4; ++j) {
            float4 wv = *reinterpret_cast<const float4*>(&Wl[(k + j) * OUTF + fc * 4]);
#pragma unroll
            for (int i = 0; i < 4; ++i) {
                float xs = (&xv[i].x)[j];
                acc[i][0] = fmaf(xs, wv.x, acc[i][0]);
                acc[i][1] = fmaf(xs, wv.y, acc[i][1]);
                acc[i][2] = fmaf(xs, wv.z, acc[i][2]);
                acc[i][3] = fmaf(xs, wv.w, acc[i][3]);
            }
        }
    }

    float asv[4], adv[4];
#pragma unroll
    for (int j = 0; j < 4; ++j) { asv[j] = a_s[fc * 4 + j]; adv[j] = a_d[fc * 4 + j]; }

#pragma unroll
    for (int i = 0; i < 4; ++i) {
        float ps = acc[i][0] * asv[0] + acc[i][1] * asv[1] +
                   acc[i][2] * asv[2] + acc[i][3] * asv[3];
        float pd = acc[i][0] * adv[0] + acc[i][1] * adv[1] +
                   acc[i][2] * adv[2] + acc[i][3] * adv[3];
#pragma unroll
        for (int off = FC >> 1; off; off >>= 1) {
            ps += __shfl_xor(ps, off, FC);
            pd += __shfl_xor(pd, off, FC);
        }
        int node = n0 + i;
        if (node < n) {
            *reinterpret_cast<float4*>(&h[(size_t)node * OUTF + fc * 4]) =
                make_float4(acc[i][0], acc[i][1], acc[i][2], acc[i][3]);
            if (fc == 0) { hs[node] = ps; hd[node] = pd; }
        }
    }
}

// ---------------------------------------------------------------------------
// Per-destination-node online-softmax aggregation. One wave per node,
// lane = feature, edge loop chunked by U=8 for gather ILP.
// ---------------------------------------------------------------------------
template <int F>
__global__ __launch_bounds__(256) void aggregate(
    const float* __restrict__ h, const float* __restrict__ hs,
    const float* __restrict__ hd, const int* __restrict__ rp,
    const int* __restrict__ cs, const float* __restrict__ b,
    float* __restrict__ out, int n) {
    int wid  = (blockIdx.x * blockDim.x + threadIdx.x) >> 6;
    int lane = threadIdx.x & 63;
    if (wid >= n) return;
    int node = wid;
    int beg = rp[node], end = rp[node + 1];
    float hdn = hd[node];
    int fl = lane & (F - 1);
    float bb = b[fl];

    constexpr int U = 8;
    float m = -1e30f, s = 0.f, acc = 0.f;

    for (int j = beg; j < end; j += U) {
        int srcs[U];
#pragma unroll
        for (int u = 0; u < U; ++u) {
            int idx = j + u;
            srcs[u] = cs[(idx < end) ? idx : (end - 1)];
        }
        float ls[U];
#pragma unroll
        for (int u = 0; u < U; ++u) ls[u] = hs[srcs[u]];
        float hv[U];
#pragma unroll
        for (int u = 0; u < U; ++u) hv[u] = h[(size_t)srcs[u] * F + fl];

        float lmax = -1e30f;
#pragma unroll
        for (int u = 0; u < U; ++u) {
            float l = ls[u] + hdn;
            l = (l > 0.f) ? l : NEG_SLOPE * l;
            ls[u] = (j + u < end) ? l : -1e30f;
            lmax = fmaxf(lmax, ls[u]);
        }
        float mn = fmaxf(m, lmax);
        float sc = __expf(m - mn);
        s *= sc;
        acc *= sc;
#pragma unroll
        for (int u = 0; u < U; ++u) {
            float w = __expf(ls[u] - mn);
            s += w;
            acc = fmaf(w, hv[u], acc);
        }
        m = mn;
    }

    float res = acc / (s + 1e-16f) + bb;
    res = fmaxf(res, 0.f);
    if (lane < F) out[(size_t)node * F + lane] = res;
}

// ---------------------------------------------------------------------------
// Global mean pool (batch is sorted): LDS pre-reduction then global atomics
// ---------------------------------------------------------------------------
__global__ void pool_kernel(const float* __restrict__ x, const int* __restrict__ batch,
                            float* __restrict__ pool, float* __restrict__ gcnt, int n) {
    __shared__ float lp[64 * 32];
    __shared__ float lc[64];
    int tid = threadIdx.x;
    for (int i = tid; i < 64 * 32; i += 256) lp[i] = 0.f;
    if (tid < 64) lc[tid] = 0.f;
    __syncthreads();
    int f = tid % 32, r = tid / 32;
    int base = blockIdx.x * 64;
    for (int i = r; i < 64; i += 8) {
        int node = base + i;
        if (node < n) {
            int g = batch[node];
            atomicAdd(&lp[g * 32 + f], x[(size_t)node * 32 + f]);
            if (f == 0) atomicAdd(&lc[g], 1.f);
        }
    }
    __syncthreads();
    for (int i = tid; i < 64 * 32; i += 256)
        if (lp[i] != 0.f) atomicAdd(&pool[i], lp[i]);
    if (tid < 64 && lc[tid] != 0.f) atomicAdd(&gcnt[tid], lc[tid]);
}

__global__ void finalize(const float* __restrict__ pool, const float* __restrict__ gcnt,
                         float* __restrict__ out, int total) {
    int i = blockIdx.x * blockDim.x + threadIdx.x;
    if (i >= total) return;
    out[i] = pool[i] / fmaxf(gcnt[i / 32], 1.f);
}

// ---------------------------------------------------------------------------
extern "C" void kernel_launch(void* const* d_in, const int* in_sizes, int n_in,
                              void* d_out, int out_size, void* d_ws, size_t ws_size,
                              hipStream_t stream) {
    const float* x    = (const float*)d_in[0];
    const int*   ei   = (const int*)d_in[1];
    const int*   batch= (const int*)d_in[2];
    const float* W1   = (const float*)d_in[3];
    const float* as1  = (const float*)d_in[4];
    const float* ad1  = (const float*)d_in[5];
    const float* b1   = (const float*)d_in[6];
    const float* W2   = (const float*)d_in[7];
    const float* as2  = (const float*)d_in[8];
    const float* ad2  = (const float*)d_in[9];
    const float* b2   = (const float*)d_in[10];
    const float* W3   = (const float*)d_in[11];
    const float* as3  = (const float*)d_in[12];
    const float* ad3  = (const float*)d_in[13];
    const float* b3   = (const float*)d_in[14];
    float* out = (float*)d_out;

    const int N  = in_sizes[0] / 128;
    const int E  = in_sizes[1] / 2;
    const int ET = E + N;
    const int G  = 64;
    const int NB = (N + 511) / 512;        // coarse buckets (512 nodes each)

    char* p = (char*)d_ws;
    auto alloc = [&](size_t bytes) {
        char* r = p;
        p += (bytes + 255) & ~(size_t)255;
        return r;
    };
    int*   cnt    = (int*)alloc((size_t)N * 4);
    int*   rp     = (int*)alloc((size_t)(N + 1) * 4);
    int*   part   = (int*)alloc(1024);
    int*   bcur   = (int*)alloc(1024);
    int*   cs     = (int*)alloc((size_t)ET * 4);
    float* hbuf   = (float*)alloc((size_t)N * 64 * 4);
    float* hs     = (float*)alloc((size_t)N * 4);
    float* hd     = (float*)alloc((size_t)N * 4);
    float* xA     = (float*)alloc((size_t)N * 64 * 4);
    float* xB     = (float*)alloc((size_t)N * 64 * 4);
    float* pool   = (float*)alloc((size_t)G * 32 * 4);
    float* gcnt   = (float*)alloc((size_t)G * 4);
    // ebuf (bucket-ordered (src,dst) pairs, ET*8 B) aliases xB (N*256 B):
    // CSR build finishes before layer 2 writes xB.
    int2*  ebuf   = (int2*)xB;

    // ---- CSR by destination (shared across all 3 layers) ----
    hipMemsetAsync(cnt, 0, (size_t)N * 4, stream);
    int eb = (ET + 255) / 256;
    count_edges<<<eb, 256, 0, stream>>>(ei, cnt, E, ET);
    int nb = (N + 1023) / 1024;
    scan1<<<nb, 256, 0, stream>>>(cnt, part, N);
    scan2<<<1, 256, 0, stream>>>(part, nb, rp, N);
    scan3<<<nb, 256, 0, stream>>>(cnt, part, rp, N);
    bcur_init<<<1, 256, 0, stream>>>(rp, bcur, N, NB);
    int bb = (ET + 256 * BIN_K - 1) / (256 * BIN_K);
    bin_edges<<<bb, 256, 0, stream>>>(ei, bcur, ebuf, E, ET);
    local_fill<<<NB, 256, 0, stream>>>(ebuf, rp, cs, N);

    int gb = (N + 63) / 64;
    int ab = (N + 3) / 4;

    // ---- layer 1: 128 -> 64 ----
    gemm_attn<128, 64><<<gb, 256, 0, stream>>>(x, W1, as1, ad1, hbuf, hs, hd, N);
    aggregate<64><<<ab, 256, 0, stream>>>(hbuf, hs, hd, rp, cs, b1, xA, N);
    // ---- layer 2: 64 -> 64 ----
    gemm_attn<64, 64><<<gb, 256, 0, stream>>>(xA, W2, as2, ad2, hbuf, hs, hd, N);
    aggregate<64><<<ab, 256, 0, stream>>>(hbuf, hs, hd, rp, cs, b2, xB, N);
    // ---- layer 3: 64 -> 32 ----
    gemm_attn<64, 32><<<gb, 128, 0, stream>>>(xB, W3, as3, ad3, hbuf, hs, hd, N);
    aggregate<32><<<ab, 256, 0, stream>>>(hbuf, hs, hd, rp, cs, b3, xA, N);

    // ---- global mean pool ----
    hipMemsetAsync(pool, 0, (size_t)G * 32 * 4, stream);
    hipMemsetAsync(gcnt, 0, (size_t)G * 4, stream);
    pool_kernel<<<(N + 63) / 64, 256, 0, stream>>>(xA, batch, pool, gcnt, N);
    finalize<<<(G * 32 + 255) / 256, 256, 0, stream>>>(pool, gcnt, out, G * 32);
}

// Round 4
// 390.191 us; speedup vs baseline: 2.0631x; 1.1135x over previous
//
#include <hip/hip_runtime.h>
#include <cstdint>
#include <cstddef>

#define NEG_SLOPE 0.2f

// ---------------------------------------------------------------------------
// CSR build: count -> scan (3 kernels) -> bin -> local fill
// ---------------------------------------------------------------------------
__global__ void count_edges(const int* __restrict__ ei, int* __restrict__ cnt,
                            int E, int total) {
    int e = blockIdx.x * blockDim.x + threadIdx.x;
    if (e >= total) return;
    int dst = (e < E) ? ei[E + e] : (e - E);   // self-loops appended
    atomicAdd(&cnt[dst], 1);
}

__global__ void scan1(const int* __restrict__ cnt, int* __restrict__ part, int n) {
    __shared__ int red[256];
    int base = blockIdx.x * 1024;
    int s = 0;
    for (int i = threadIdx.x; i < 1024; i += 256) {
        int idx = base + i;
        s += (idx < n) ? cnt[idx] : 0;
    }
    red[threadIdx.x] = s;
    __syncthreads();
    for (int off = 128; off; off >>= 1) {
        if (threadIdx.x < off) red[threadIdx.x] += red[threadIdx.x + off];
        __syncthreads();
    }
    if (threadIdx.x == 0) part[blockIdx.x] = red[0];
}

// single block: exclusive scan of partials (nb <= 256); also writes rp[n]=total
__global__ void scan2(int* __restrict__ part, int nb, int* __restrict__ rp, int n) {
    __shared__ int sc[256];
    int t = threadIdx.x;
    int v = (t < nb) ? part[t] : 0;
    sc[t] = v;
    __syncthreads();
    for (int off = 1; off < 256; off <<= 1) {
        int x = (t >= off) ? sc[t - off] : 0;
        __syncthreads();
        sc[t] += x;
        __syncthreads();
    }
    if (t < nb) part[t] = sc[t] - v;        // exclusive
    if (t == 255) rp[n] = sc[255];          // total edge count
}

__global__ void scan3(const int* __restrict__ cnt, const int* __restrict__ part,
                      int* __restrict__ rp, int n) {
    __shared__ int tsum[256];
    int base = blockIdx.x * 1024;
    int t = threadIdx.x;
    int v[4];
    int loc = 0;
#pragma unroll
    for (int i = 0; i < 4; ++i) {
        int idx = base + t * 4 + i;
        v[i] = (idx < n) ? cnt[idx] : 0;
        loc += v[i];
    }
    tsum[t] = loc;
    __syncthreads();
    for (int off = 1; off < 256; off <<= 1) {
        int x = (t >= off) ? tsum[t - off] : 0;
        __syncthreads();
        tsum[t] += x;
        __syncthreads();
    }
    int excl = tsum[t] - loc + part[blockIdx.x];
#pragma unroll
    for (int i = 0; i < 4; ++i) {
        int idx = base + t * 4 + i;
        if (idx < n) rp[idx] = excl;
        excl += v[i];
    }
}

// bucket cursors = CSR offset of each bucket's first node (bucket = 512 nodes)
__global__ void bcur_init(const int* __restrict__ rp, int* __restrict__ bcur,
                          int n, int nb) {
    int t = threadIdx.x;
    if (t < nb) bcur[t] = rp[min(t * 512, n)];
    else if (t < 256) bcur[t] = 0;
}

// ---------------------------------------------------------------------------
// Pass 1: bin edges into 512-node coarse buckets.
// ---------------------------------------------------------------------------
#define BIN_K 16   // edges per thread; chunk = 256*16 = 4096
__global__ __launch_bounds__(256) void bin_edges(
    const int* __restrict__ ei, int* __restrict__ bcur,
    int2* __restrict__ ebuf, int E, int total) {
    __shared__ int lhist[256];
    __shared__ int lbase[256];
    int tid = threadIdx.x;
    lhist[tid] = 0;
    __syncthreads();
    int base_e = blockIdx.x * (256 * BIN_K);
    int s[BIN_K], d[BIN_K], bk[BIN_K];
#pragma unroll
    for (int k = 0; k < BIN_K; ++k) {
        int e = base_e + tid + k * 256;
        bool v = e < total;
        int ee = v ? e : 0;
        if (ee < E) { s[k] = ei[ee]; d[k] = ei[E + ee]; }
        else        { s[k] = d[k] = ee - E; }
        bk[k] = v ? (d[k] >> 9) : -1;
        if (v) atomicAdd(&lhist[bk[k]], 1);
    }
    __syncthreads();
    int h = lhist[tid];
    lbase[tid] = (h > 0) ? atomicAdd(&bcur[tid], h) : 0;
    __syncthreads();
    lhist[tid] = 0;
    __syncthreads();
#pragma unroll
    for (int k = 0; k < BIN_K; ++k) {
        if (bk[k] >= 0) {
            int r = atomicAdd(&lhist[bk[k]], 1);
            ebuf[(size_t)lbase[bk[k]] + r] = make_int2(s[k], d[k]);
        }
    }
}

// ---------------------------------------------------------------------------
// Pass 2: one block per bucket; node cursors in LDS, writes stay local.
// ---------------------------------------------------------------------------
__global__ __launch_bounds__(256) void local_fill(
    const int2* __restrict__ ebuf, const int* __restrict__ rp,
    int* __restrict__ cs, int n) {
    __shared__ int lcur[512];
    int node0 = blockIdx.x * 512;
    int nodes = min(512, n - node0);
    int tid = threadIdx.x;
    for (int j = tid; j < nodes; j += 256) lcur[j] = rp[node0 + j];
    __syncthreads();
    int beg = rp[node0];
    int end = rp[node0 + nodes];
    for (int base = beg; base < end; base += 256 * 8) {
        int2 pr[8];
        int idx[8];
#pragma unroll
        for (int u = 0; u < 8; ++u) {
            idx[u] = base + tid + u * 256;
            pr[u] = ebuf[(idx[u] < end) ? idx[u] : beg];
        }
#pragma unroll
        for (int u = 0; u < 8; ++u) {
            if (idx[u] < end) {
                int pos = atomicAdd(&lcur[pr[u].y - node0], 1);
                cs[pos] = pr[u].x;
            }
        }
    }
}

// ---------------------------------------------------------------------------
// Fused projection + attention dots:  h = x @ W ; hs = h@a_s ; hd = h@a_d
// ---------------------------------------------------------------------------
template <int INF, int OUTF>
__global__ void gemm_attn(const float* __restrict__ x, const float* __restrict__ W,
                          const float* __restrict__ a_s, const float* __restrict__ a_d,
                          float* __restrict__ h, float* __restrict__ hs,
                          float* __restrict__ hd, int n) {
    constexpr int FC  = OUTF / 4;          // threads along feature dim
    constexpr int NPB = 64;                // nodes per block
    constexpr int NT  = FC * (NPB / 4);    // threads per block
    __shared__ float Wl[INF * OUTF];
    int tid = threadIdx.x;
    for (int i = tid; i < INF * OUTF; i += NT) Wl[i] = W[i];
    __syncthreads();

    int fc = tid % FC;
    int nc = tid / FC;                     // 0..15
    int n0 = blockIdx.x * NPB + nc * 4;
    int ni[4];
#pragma unroll
    for (int i = 0; i < 4; ++i) { int v = n0 + i; ni[i] = (v < n) ? v : (n - 1); }

    float acc[4][4] = {};
#pragma unroll 2
    for (int k = 0; k < INF; k += 4) {
        float4 xv[4];
#pragma unroll
        for (int i = 0; i < 4; ++i)
            xv[i] = *reinterpret_cast<const float4*>(&x[(size_t)ni[i] * INF + k]);
#pragma unroll
        for (int j = 0; j < 4; ++j) {
            float4 wv = *reinterpret_cast<const float4*>(&Wl[(k + j) * OUTF + fc * 4]);
#pragma unroll
            for (int i = 0; i < 4; ++i) {
                float xs = (&xv[i].x)[j];
                acc[i][0] = fmaf(xs, wv.x, acc[i][0]);
                acc[i][1] = fmaf(xs, wv.y, acc[i][1]);
                acc[i][2] = fmaf(xs, wv.z, acc[i][2]);
                acc[i][3] = fmaf(xs, wv.w, acc[i][3]);
            }
        }
    }

    float asv[4], adv[4];
#pragma unroll
    for (int j = 0; j < 4; ++j) { asv[j] = a_s[fc * 4 + j]; adv[j] = a_d[fc * 4 + j]; }

#pragma unroll
    for (int i = 0; i < 4; ++i) {
        float ps = acc[i][0] * asv[0] + acc[i][1] * asv[1] +
                   acc[i][2] * asv[2] + acc[i][3] * asv[3];
        float pd = acc[i][0] * adv[0] + acc[i][1] * adv[1] +
                   acc[i][2] * adv[2] + acc[i][3] * adv[3];
#pragma unroll
        for (int off = FC >> 1; off; off >>= 1) {
            ps += __shfl_xor(ps, off, FC);
            pd += __shfl_xor(pd, off, FC);
        }
        int node = n0 + i;
        if (node < n) {
            *reinterpret_cast<float4*>(&h[(size_t)node * OUTF + fc * 4]) =
                make_float4(acc[i][0], acc[i][1], acc[i][2], acc[i][3]);
            if (fc == 0) { hs[node] = ps; hd[node] = pd; }
        }
    }
}

// ---------------------------------------------------------------------------
// Wave-cooperative online-softmax aggregation.
// F lanes per node (F=64: 1 node/wave; F=32: 2 nodes/wave).
// Phase 1 per chunk of F edges: lane e computes logit of edge e (one exp per
// EDGE, not per lane); shfl_xor max/sum; one rescale.
// Phase 2: per edge, broadcast (src,w) via shfl (DS pipe), coalesced h-row
// load + fmac, manually batched 8-wide for gather ILP.
// ---------------------------------------------------------------------------
template <int F>
__global__ __launch_bounds__(256) void aggregate(
    const float* __restrict__ h, const float* __restrict__ hs,
    const float* __restrict__ hd, const int* __restrict__ rp,
    const int* __restrict__ cs, const float* __restrict__ b,
    float* __restrict__ out, int n) {
    constexpr int NPW = 64 / F;            // nodes per wave
    int wid  = (blockIdx.x * blockDim.x + threadIdx.x) >> 6;
    int lane = threadIdx.x & 63;
    int fl   = lane % F;
    int node = wid * NPW + lane / F;
    if (node >= n) return;
    int beg = rp[node], end = rp[node + 1];
    float hdn = hd[node];
    float bb  = b[fl];

    float m = -1e30f, s = 0.f, acc = 0.f;

    for (int base = beg; base < end; base += F) {
        // ---- phase 1: lane-parallel logits over this chunk's edges ----
        int e = base + fl;
        bool v = e < end;
        int src = cs[v ? e : beg];
        float l = hs[src] + hdn;
        l = (l > 0.f) ? l : NEG_SLOPE * l;
        l = v ? l : -1e30f;
        float lm = l;
#pragma unroll
        for (int off = F >> 1; off; off >>= 1)
            lm = fmaxf(lm, __shfl_xor(lm, off, F));
        float mn = fmaxf(m, lm);
        float w = __expf(l - mn);          // one exp per edge
        float ws = w;
#pragma unroll
        for (int off = F >> 1; off; off >>= 1)
            ws += __shfl_xor(ws, off, F);
        float sc = __expf(m - mn);
        s = fmaf(s, sc, ws);
        acc *= sc;
        m = mn;

        // ---- phase 2: weighted feature accumulation, 8-wide batches ----
        int cc = min(F, end - base);
        for (int e2 = 0; e2 < cc; e2 += 8) {
            float wv[8], hv[8];
#pragma unroll
            for (int u = 0; u < 8; ++u) {
                int j  = e2 + u;
                int jj = (j < cc) ? j : 0;
                int   se = __shfl(src, jj, F);
                float we = __shfl(w,   jj, F);
                wv[u] = (j < cc) ? we : 0.f;
                hv[u] = h[(size_t)se * F + fl];
            }
#pragma unroll
            for (int u = 0; u < 8; ++u)
                acc = fmaf(wv[u], hv[u], acc);
        }
    }

    float res = acc / (s + 1e-16f) + bb;
    out[(size_t)node * F + fl] = fmaxf(res, 0.f);
}

// ---------------------------------------------------------------------------
// Global mean pool (batch is sorted): LDS pre-reduction then global atomics
// ---------------------------------------------------------------------------
__global__ void pool_kernel(const float* __restrict__ x, const int* __restrict__ batch,
                            float* __restrict__ pool, float* __restrict__ gcnt, int n) {
    __shared__ float lp[64 * 32];
    __shared__ float lc[64];
    int tid = threadIdx.x;
    for (int i = tid; i < 64 * 32; i += 256) lp[i] = 0.f;
    if (tid < 64) lc[tid] = 0.f;
    __syncthreads();
    int f = tid % 32, r = tid / 32;
    int base = blockIdx.x * 64;
    for (int i = r; i < 64; i += 8) {
        int node = base + i;
        if (node < n) {
            int g = batch[node];
            atomicAdd(&lp[g * 32 + f], x[(size_t)node * 32 + f]);
            if (f == 0) atomicAdd(&lc[g], 1.f);
        }
    }
    __syncthreads();
    for (int i = tid; i < 64 * 32; i += 256)
        if (lp[i] != 0.f) atomicAdd(&pool[i], lp[i]);
    if (tid < 64 && lc[tid] != 0.f) atomicAdd(&gcnt[tid], lc[tid]);
}

__global__ void finalize(const float* __restrict__ pool, const float* __restrict__ gcnt,
                         float* __restrict__ out, int total) {
    int i = blockIdx.x * blockDim.x + threadIdx.x;
    if (i >= total) return;
    out[i] = pool[i] / fmaxf(gcnt[i / 32], 1.f);
}

// ---------------------------------------------------------------------------
extern "C" void kernel_launch(void* const* d_in, const int* in_sizes, int n_in,
                              void* d_out, int out_size, void* d_ws, size_t ws_size,
                              hipStream_t stream) {
    const float* x    = (const float*)d_in[0];
    const int*   ei   = (const int*)d_in[1];
    const int*   batch= (const int*)d_in[2];
    const float* W1   = (const float*)d_in[3];
    const float* as1  = (const float*)d_in[4];
    const float* ad1  = (const float*)d_in[5];
    const float* b1   = (const float*)d_in[6];
    const float* W2   = (const float*)d_in[7];
    const float* as2  = (const float*)d_in[8];
    const float* ad2  = (const float*)d_in[9];
    const float* b2   = (const float*)d_in[10];
    const float* W3   = (const float*)d_in[11];
    const float* as3  = (const float*)d_in[12];
    const float* ad3  = (const float*)d_in[13];
    const float* b3   = (const float*)d_in[14];
    float* out = (float*)d_out;

    const int N  = in_sizes[0] / 128;
    const int E  = in_sizes[1] / 2;
    const int ET = E + N;
    const int G  = 64;
    const int NB = (N + 511) / 512;        // coarse buckets (512 nodes each)

    char* p = (char*)d_ws;
    auto alloc = [&](size_t bytes) {
        char* r = p;
        p += (bytes + 255) & ~(size_t)255;
        return r;
    };
    int*   cnt    = (int*)alloc((size_t)N * 4);
    int*   rp     = (int*)alloc((size_t)(N + 1) * 4);
    int*   part   = (int*)alloc(1024);
    int*   bcur   = (int*)alloc(1024);
    int*   cs     = (int*)alloc((size_t)ET * 4);
    float* hbuf   = (float*)alloc((size_t)N * 64 * 4);
    float* hs     = (float*)alloc((size_t)N * 4);
    float* hd     = (float*)alloc((size_t)N * 4);
    float* xA     = (float*)alloc((size_t)N * 64 * 4);
    float* xB     = (float*)alloc((size_t)N * 64 * 4);
    float* pool   = (float*)alloc((size_t)G * 32 * 4);
    float* gcnt   = (float*)alloc((size_t)G * 4);
    // ebuf aliases xB: CSR build finishes before layer 2 writes xB.
    int2*  ebuf   = (int2*)xB;

    // ---- CSR by destination (shared across all 3 layers) ----
    hipMemsetAsync(cnt, 0, (size_t)N * 4, stream);
    int eb = (ET + 255) / 256;
    count_edges<<<eb, 256, 0, stream>>>(ei, cnt, E, ET);
    int nb = (N + 1023) / 1024;
    scan1<<<nb, 256, 0, stream>>>(cnt, part, N);
    scan2<<<1, 256, 0, stream>>>(part, nb, rp, N);
    scan3<<<nb, 256, 0, stream>>>(cnt, part, rp, N);
    bcur_init<<<1, 256, 0, stream>>>(rp, bcur, N, NB);
    int bb = (ET + 256 * BIN_K - 1) / (256 * BIN_K);
    bin_edges<<<bb, 256, 0, stream>>>(ei, bcur, ebuf, E, ET);
    local_fill<<<NB, 256, 0, stream>>>(ebuf, rp, cs, N);

    int gb = (N + 63) / 64;
    int ab64 = (N + 3) / 4;        // 4 waves/block, 1 node/wave
    int ab32 = (N + 7) / 8;        // 4 waves/block, 2 nodes/wave

    // ---- layer 1: 128 -> 64 ----
    gemm_attn<128, 64><<<gb, 256, 0, stream>>>(x, W1, as1, ad1, hbuf, hs, hd, N);
    aggregate<64><<<ab64, 256, 0, stream>>>(hbuf, hs, hd, rp, cs, b1, xA, N);
    // ---- layer 2: 64 -> 64 ----
    gemm_attn<64, 64><<<gb, 256, 0, stream>>>(xA, W2, as2, ad2, hbuf, hs, hd, N);
    aggregate<64><<<ab64, 256, 0, stream>>>(hbuf, hs, hd, rp, cs, b2, xB, N);
    // ---- layer 3: 64 -> 32 ----
    gemm_attn<64, 32><<<gb, 128, 0, stream>>>(xB, W3, as3, ad3, hbuf, hs, hd, N);
    aggregate<32><<<ab32, 256, 0, stream>>>(hbuf, hs, hd, rp, cs, b3, xA, N);

    // ---- global mean pool ----
    hipMemsetAsync(pool, 0, (size_t)G * 32 * 4, stream);
    hipMemsetAsync(gcnt, 0, (size_t)G * 4, stream);
    pool_kernel<<<(N + 63) / 64, 256, 0, stream>>>(xA, batch, pool, gcnt, N);
    finalize<<<(G * 32 + 255) / 256, 256, 0, stream>>>(pool, gcnt, out, G * 32);
}